// Round 1
// baseline (1521.087 us; speedup 1.0000x reference)
//
#include <hip/hip_runtime.h>

#define BB 16
#define TT 1024
#define NF 512
#define HH 8
#define DD 64

// ---------------------------------------------------------------------------
// Generic 512-K tiled f32 GEMM: C = A(M x 512) @ W(512 x 512) + bias, with
// output-layout modes:
//   MODE 0: P layout   out[(h*T + row)*64 + d]            (pos projection)
//   MODE 1: BHTD layout out[((b*H+h)*T + t)*64 + d]        (q, v)
//   MODE 2: BHTD layout + add Padd[(h*T + t)*64 + d]       (kp = k + p)
//   MODE 4: row-major  out[row*512 + col]                  (final)
// ---------------------------------------------------------------------------
template<int MODE>
__global__ __launch_bounds__(256) void gemm512(const float* __restrict__ A,
                                               const float* __restrict__ W,
                                               const float* __restrict__ bias,
                                               const float* __restrict__ Padd,
                                               float* __restrict__ out, int M)
{
    __shared__ float As[16][65];
    __shared__ float Ws[16][64];
    const int tid  = threadIdx.x;
    const int row0 = blockIdx.x * 64;
    const int col0 = blockIdx.y * 64;
    const int tr = tid & 15, tc = tid >> 4;     // 16 x 16 thread grid, 4x4 each
    const int lm = tid >> 2;                    // 0..63 : A-tile row
    const int lk = (tid & 3) * 4;               // 0..12 : A-tile k offset
    const int wk = tid >> 4;                    // 0..15 : W-tile k row
    const int wn = (tid & 15) * 4;              // 0..60 : W-tile col offset

    float acc[4][4] = {};

    for (int k0 = 0; k0 < 512; k0 += 16) {
        const float4 av = *reinterpret_cast<const float4*>(&A[(row0 + lm) * 512 + k0 + lk]);
        const float4 wv = *reinterpret_cast<const float4*>(&W[(k0 + wk) * 512 + col0 + wn]);
        __syncthreads();   // protect previous iteration's LDS reads
        As[lk + 0][lm] = av.x;
        As[lk + 1][lm] = av.y;
        As[lk + 2][lm] = av.z;
        As[lk + 3][lm] = av.w;
        *reinterpret_cast<float4*>(&Ws[wk][wn]) = wv;
        __syncthreads();
#pragma unroll
        for (int kk = 0; kk < 16; ++kk) {
            float a[4], b[4];
#pragma unroll
            for (int i = 0; i < 4; ++i) a[i] = As[kk][tr * 4 + i];
#pragma unroll
            for (int j = 0; j < 4; ++j) b[j] = Ws[kk][tc * 4 + j];
#pragma unroll
            for (int i = 0; i < 4; ++i)
#pragma unroll
                for (int j = 0; j < 4; ++j)
                    acc[i][j] = fmaf(a[i], b[j], acc[i][j]);
        }
    }

#pragma unroll
    for (int i = 0; i < 4; ++i) {
        const int r = row0 + tr * 4 + i;
#pragma unroll
        for (int j = 0; j < 4; ++j) {
            const int c = col0 + tc * 4 + j;
            float val = acc[i][j] + (bias ? bias[c] : 0.f);
            if (MODE == 4) {
                out[r * 512 + c] = val;
            } else if (MODE == 0) {
                const int h = c >> 6, d = c & 63;
                out[(h * TT + r) * 64 + d] = val;
            } else {
                const int b_ = r >> 10, t_ = r & 1023;
                const int h = c >> 6, d = c & 63;
                if (MODE == 2) val += Padd[(h * TT + t_) * 64 + d];
                out[((b_ * HH + h) * TT + t_) * 64 + d] = val;
            }
        }
    }
}

// ---------------------------------------------------------------------------
// sb[b,h,s] = ( u[h]·kp[b,h,s] + (v[h]-u[h])·p[h,s] ) / 8 + mask[b,s]
// One wave per (b,h,s); 64 lanes over d; shuffle reduce.
// ---------------------------------------------------------------------------
__global__ __launch_bounds__(256) void sbias_kernel(const float* __restrict__ kp,
                                                    const float* __restrict__ p,
                                                    const float* __restrict__ pbu,
                                                    const float* __restrict__ pbv,
                                                    const float* __restrict__ mask,
                                                    float* __restrict__ sb)
{
    const int w    = blockIdx.x * 4 + (threadIdx.x >> 6);
    const int lane = threadIdx.x & 63;
    const int s = w & 1023;
    const int h = (w >> 10) & 7;
    const int b = w >> 13;
    const float u  = pbu[h * 64 + lane];
    const float wv = pbv[h * 64 + lane] - u;
    const float kv = kp[((b * HH + h) * TT + s) * 64 + lane];
    const float pv = p[(h * TT + s) * 64 + lane];
    float val = u * kv + wv * pv;
#pragma unroll
    for (int off = 32; off; off >>= 1) val += __shfl_xor(val, off);
    if (lane == 0) sb[(b * HH + h) * TT + s] = val * 0.125f + mask[b * TT + s];
}

// ---------------------------------------------------------------------------
// Fused flash attention: per block one (b,h) and a 64-row Q tile.
// score[t,s] = q[t]·kp[s]/8 + sb[s];  online softmax;  out = P@V / l.
// ---------------------------------------------------------------------------
__global__ __launch_bounds__(256) void attn_kernel(const float* __restrict__ q,
                                                   const float* __restrict__ kp,
                                                   const float* __restrict__ v,
                                                   const float* __restrict__ sb,
                                                   float* __restrict__ ao)
{
    __shared__ float Qs[64][65];
    __shared__ float Ks[64][65];   // doubles as P (probs) storage
    __shared__ float Vs[64][65];
    __shared__ float sbs[64];
    __shared__ float corr[64];
    __shared__ float lrow[64];

    const int tid = threadIdx.x;
    const int t0  = blockIdx.x * 64;
    const int h   = blockIdx.y;
    const int b   = blockIdx.z;
    const int tr = tid & 15, tc = tid >> 4;

    const float* qbase  = q  + ((size_t)(b * HH + h) * TT + t0) * 64;
    const float* kbase  = kp + (size_t)(b * HH + h) * TT * 64;
    const float* vbase  = v  + (size_t)(b * HH + h) * TT * 64;
    const float* sbbase = sb + (size_t)(b * HH + h) * TT;

    // load Q tile (4096 floats)
#pragma unroll
    for (int i = 0; i < 4; ++i) {
        const int idx = i * 1024 + tid * 4;
        const int r = idx >> 6, c = idx & 63;
        const float4 qv = *reinterpret_cast<const float4*>(&qbase[idx]);
        Qs[r][c + 0] = qv.x; Qs[r][c + 1] = qv.y; Qs[r][c + 2] = qv.z; Qs[r][c + 3] = qv.w;
    }

    float m = -1e30f, l = 0.f;          // owned by tid < 64 (row = tid)
    float oacc[4][4] = {};

    for (int s0 = 0; s0 < TT; s0 += 64) {
        // stage K, V tiles + sb
#pragma unroll
        for (int i = 0; i < 4; ++i) {
            const int idx = i * 1024 + tid * 4;
            const int r = idx >> 6, c = idx & 63;
            const float4 kv = *reinterpret_cast<const float4*>(&kbase[s0 * 64 + idx]);
            const float4 vv = *reinterpret_cast<const float4*>(&vbase[s0 * 64 + idx]);
            Ks[r][c + 0] = kv.x; Ks[r][c + 1] = kv.y; Ks[r][c + 2] = kv.z; Ks[r][c + 3] = kv.w;
            Vs[r][c + 0] = vv.x; Vs[r][c + 1] = vv.y; Vs[r][c + 2] = vv.z; Vs[r][c + 3] = vv.w;
        }
        if (tid < 64) sbs[tid] = sbbase[s0 + tid];
        __syncthreads();

        // scores in registers
        float sc[4][4] = {};
#pragma unroll 8
        for (int d = 0; d < 64; ++d) {
            float a[4], bk[4];
#pragma unroll
            for (int i = 0; i < 4; ++i) a[i]  = Qs[tr * 4 + i][d];
#pragma unroll
            for (int j = 0; j < 4; ++j) bk[j] = Ks[tc * 4 + j][d];
#pragma unroll
            for (int i = 0; i < 4; ++i)
#pragma unroll
                for (int j = 0; j < 4; ++j)
                    sc[i][j] = fmaf(a[i], bk[j], sc[i][j]);
        }
        __syncthreads();   // everyone done reading Ks

        // write scores (scaled + biased) into P (= Ks storage)
#pragma unroll
        for (int i = 0; i < 4; ++i)
#pragma unroll
            for (int j = 0; j < 4; ++j)
                Ks[tr * 4 + i][tc * 4 + j] = sc[i][j] * 0.125f + sbs[tc * 4 + j];
        __syncthreads();

        // online softmax, one thread per row
        if (tid < 64) {
            float rmax = -1e30f;
            for (int j = 0; j < 64; ++j) rmax = fmaxf(rmax, Ks[tid][j]);
            const float nm = fmaxf(m, rmax);
            const float cf = expf(m - nm);
            float rs = 0.f;
            for (int j = 0; j < 64; ++j) {
                const float pj = expf(Ks[tid][j] - nm);
                Ks[tid][j] = pj;
                rs += pj;
            }
            l = l * cf + rs;
            m = nm;
            corr[tid] = cf;
        }
        __syncthreads();

        // rescale + PV accumulate
        float cfs[4];
#pragma unroll
        for (int i = 0; i < 4; ++i) cfs[i] = corr[tr * 4 + i];
#pragma unroll
        for (int i = 0; i < 4; ++i)
#pragma unroll
            for (int j = 0; j < 4; ++j) oacc[i][j] *= cfs[i];

#pragma unroll 8
        for (int s = 0; s < 64; ++s) {
            float pa[4], vb[4];
#pragma unroll
            for (int i = 0; i < 4; ++i) pa[i] = Ks[tr * 4 + i][s];
#pragma unroll
            for (int j = 0; j < 4; ++j) vb[j] = Vs[s][tc * 4 + j];
#pragma unroll
            for (int i = 0; i < 4; ++i)
#pragma unroll
                for (int j = 0; j < 4; ++j)
                    oacc[i][j] = fmaf(pa[i], vb[j], oacc[i][j]);
        }
        __syncthreads();   // before next tile overwrites Ks/Vs
    }

    if (tid < 64) lrow[tid] = l;
    __syncthreads();

#pragma unroll
    for (int i = 0; i < 4; ++i) {
        const float inv = 1.f / lrow[tr * 4 + i];
        const int row = b * TT + t0 + tr * 4 + i;
#pragma unroll
        for (int j = 0; j < 4; ++j)
            ao[(size_t)row * 512 + h * 64 + tc * 4 + j] = oacc[i][j] * inv;
    }
}

// ---------------------------------------------------------------------------
extern "C" void kernel_launch(void* const* d_in, const int* in_sizes, int n_in,
                              void* d_out, int out_size, void* d_ws, size_t ws_size,
                              hipStream_t stream)
{
    const float* query   = (const float*)d_in[0];
    const float* key     = (const float*)d_in[1];
    const float* value   = (const float*)d_in[2];
    const float* pos_emb = (const float*)d_in[3];
    const float* mask    = (const float*)d_in[4];
    const float* Wq   = (const float*)d_in[5];
    const float* bq   = (const float*)d_in[6];
    const float* Wk   = (const float*)d_in[7];
    const float* bk   = (const float*)d_in[8];
    const float* Wv   = (const float*)d_in[9];
    const float* bv   = (const float*)d_in[10];
    const float* Wo   = (const float*)d_in[11];
    const float* bo   = (const float*)d_in[12];
    const float* Wpos = (const float*)d_in[13];
    const float* pbu  = (const float*)d_in[14];
    const float* pbv  = (const float*)d_in[15];
    float* out = (float*)d_out;

    float* ws = (float*)d_ws;
    float* p_ws  = ws;                               // H*T*D      = 524288
    float* q_ws  = p_ws  + (size_t)HH * TT * DD;     // B*H*T*D    = 8388608
    float* kp_ws = q_ws  + (size_t)BB * HH * TT * DD;
    float* v_ws  = kp_ws + (size_t)BB * HH * TT * DD;
    float* sb_ws = v_ws  + (size_t)BB * HH * TT * DD; // B*H*T     = 131072
    float* ao_ws = sb_ws + (size_t)BB * HH * TT;      // B*T*512   = 8388608

    const dim3 blk(256);

    // p = pos_emb @ Wpos            -> (H, T, D)
    gemm512<0><<<dim3(TT / 64, 8), blk, 0, stream>>>(pos_emb, Wpos, nullptr, nullptr, p_ws, TT);
    // q = query @ Wq + bq           -> (B, H, T, D)
    gemm512<1><<<dim3(BB * TT / 64, 8), blk, 0, stream>>>(query, Wq, bq, nullptr, q_ws, BB * TT);
    // kp = key @ Wk + bk + p        -> (B, H, T, D)
    gemm512<2><<<dim3(BB * TT / 64, 8), blk, 0, stream>>>(key, Wk, bk, p_ws, kp_ws, BB * TT);
    // v = value @ Wv + bv           -> (B, H, T, D)
    gemm512<1><<<dim3(BB * TT / 64, 8), blk, 0, stream>>>(value, Wv, bv, nullptr, v_ws, BB * TT);
    // sb[b,h,s]
    sbias_kernel<<<dim3(BB * HH * TT / 4), blk, 0, stream>>>(kp_ws, p_ws, pbu, pbv, mask, sb_ws);
    // fused attention -> ao (B, T, 512)
    attn_kernel<<<dim3(TT / 64, HH, BB), blk, 0, stream>>>(q_ws, kp_ws, v_ws, sb_ws, ao_ws);
    // out = ao @ Wo + bo
    gemm512<4><<<dim3(BB * TT / 64, 8), blk, 0, stream>>>(ao_ws, Wo, bo, nullptr, out, BB * TT);
}

// Round 2
// 257.371 us; speedup vs baseline: 5.9101x; 5.9101x over previous
//
#include <hip/hip_runtime.h>

#define BB 16
#define TT 1024
#define HH 8
#define DD 64
#define NF 512

typedef __attribute__((ext_vector_type(4))) float f4;
typedef __attribute__((ext_vector_type(8))) short s8;
typedef __attribute__((ext_vector_type(4))) unsigned short us4;
typedef unsigned short u16;

__device__ __forceinline__ u16 f2bf(float x){
    unsigned int u = __builtin_bit_cast(unsigned int, x);
    u = (u + 0x7FFFu + ((u >> 16) & 1u)) >> 16;
    return (u16)u;
}
__device__ __forceinline__ float bf2f(u16 h){
    unsigned int u = ((unsigned int)h) << 16;
    return __builtin_bit_cast(float, u);
}

// ---------------------------------------------------------------------------
// Weight prep: Wt[n][k] = bf16(W[k][n]) for Wq,Wk,Wv,Wpos; Wo -> hi/lo pair.
// 32x32 LDS tile transpose, coalesced both sides.
// ---------------------------------------------------------------------------
__global__ __launch_bounds__(256) void prep_w(const float* __restrict__ Wq,
    const float* __restrict__ Wk, const float* __restrict__ Wv,
    const float* __restrict__ Wpos, const float* __restrict__ Wo,
    u16* __restrict__ wtq, u16* __restrict__ wtk, u16* __restrict__ wtv,
    u16* __restrict__ wtp, u16* __restrict__ wohi, u16* __restrict__ wolo)
{
    __shared__ float tile[32][33];
    const int which = blockIdx.z;
    const float* W = which==0?Wq:which==1?Wk:which==2?Wv:which==3?Wpos:Wo;
    const int n0 = blockIdx.x*32, k0 = blockIdx.y*32;
    const int tc = threadIdx.x & 31, tr = threadIdx.x >> 5;
#pragma unroll
    for (int i=0;i<4;i++){ int r = tr + i*8; tile[r][tc] = W[(size_t)(k0+r)*NF + n0+tc]; }
    __syncthreads();
#pragma unroll
    for (int i=0;i<4;i++){
        int n = tr + i*8, k = tc;
        float val = tile[k][n];
        u16 hi = f2bf(val);
        size_t off = (size_t)(n0+n)*NF + k0+k;
        if (which==0) wtq[off]=hi; else if (which==1) wtk[off]=hi;
        else if (which==2) wtv[off]=hi; else if (which==3) wtp[off]=hi;
        else { wohi[off]=hi; wolo[off]=f2bf(val - bf2f(hi)); }
    }
}

// ---------------------------------------------------------------------------
// bf16 MFMA GEMM, 128x128 tile, BK=64, 4 waves (each 64x64), reg-staged A(f32)
// with inline f32->bf16 convert. XOR-swizzled LDS (^((row&7)<<4) on byte).
// MODE 0: out p_ws[(h*T+t)*64+d]    (pos, no bias)
// MODE 1: out bhtd bf16, + bias
// MODE 2: out bhtd bf16, + bias + padd (bf16, p layout)
// ---------------------------------------------------------------------------
template<int MODE>
__global__ __launch_bounds__(256) void gemm_bf16(const float* __restrict__ A,
                                                 const u16* __restrict__ Wt,
                                                 const float* __restrict__ bias,
                                                 const u16* __restrict__ padd,
                                                 u16* __restrict__ out)
{
    __shared__ __align__(16) u16 As[128*64];
    __shared__ __align__(16) u16 Bs[128*64];
    const int tid = threadIdx.x;
    const int row0 = blockIdx.x*128, col0 = blockIdx.y*128;
    const int wid = tid>>6, lane = tid&63, lm = lane&15, lg = lane>>4;
    const int wm = wid>>1, wn = wid&1;

    f4 acc[4][4];
#pragma unroll
    for (int i=0;i<4;i++)
#pragma unroll
        for (int j=0;j<4;j++) acc[i][j] = (f4){0.f,0.f,0.f,0.f};

    for (int k0=0;k0<NF;k0+=64){
        f4 areg[8]; s8 breg[4];
#pragma unroll
        for (int it=0; it<8; ++it){
            int idx = (it*256 + tid)*4;
            int m = idx>>6, k = idx&63;
            areg[it] = *(const f4*)(&A[(size_t)(row0+m)*NF + k0 + k]);
        }
#pragma unroll
        for (int it=0; it<4; ++it){
            int idx = (it*256 + tid)*8;
            int n = idx>>6, k = idx&63;
            breg[it] = *(const s8*)(&Wt[(size_t)(col0+n)*NF + k0 + k]);
        }
        __syncthreads();           // previous iteration's LDS reads done
#pragma unroll
        for (int it=0; it<8; ++it){
            int idx = (it*256+tid)*4;
            int m = idx>>6, k = idx&63;
            us4 pk;
            pk[0]=f2bf(areg[it][0]); pk[1]=f2bf(areg[it][1]);
            pk[2]=f2bf(areg[it][2]); pk[3]=f2bf(areg[it][3]);
            *(us4*)((char*)As + ((m*128 + k*2) ^ ((m&7)<<4))) = pk;
        }
#pragma unroll
        for (int it=0; it<4; ++it){
            int idx = (it*256+tid)*8;
            int n = idx>>6, k = idx&63;
            *(s8*)((char*)Bs + ((n*128 + k*2) ^ ((n&7)<<4))) = breg[it];
        }
        __syncthreads();
        s8 af[4][2], bf[4][2];
#pragma unroll
        for (int i=0;i<4;i++){
            int m = wm*64 + i*16 + lm;
#pragma unroll
            for (int c=0;c<2;c++)
                af[i][c] = *(const s8*)((char*)As + ((m*128 + c*64 + lg*16) ^ ((m&7)<<4)));
        }
#pragma unroll
        for (int j=0;j<4;j++){
            int n = wn*64 + j*16 + lm;
#pragma unroll
            for (int c=0;c<2;c++)
                bf[j][c] = *(const s8*)((char*)Bs + ((n*128 + c*64 + lg*16) ^ ((n&7)<<4)));
        }
#pragma unroll
        for (int i=0;i<4;i++)
#pragma unroll
            for (int j=0;j<4;j++)
#pragma unroll
                for (int c=0;c<2;c++)
                    acc[i][j] = __builtin_amdgcn_mfma_f32_16x16x32_bf16(af[i][c], bf[j][c], acc[i][j], 0,0,0);
    }

#pragma unroll
    for (int i=0;i<4;i++){
#pragma unroll
        for (int j=0;j<4;j++){
#pragma unroll
            for (int r=0;r<4;r++){
                const int m = row0 + wm*64 + i*16 + lg*4 + r;
                const int n = col0 + wn*64 + j*16 + lm;
                float val = acc[i][j][r];
                const int hh = n>>6, dd = n&63;
                if (MODE == 0){
                    out[(size_t)(hh*TT + m)*64 + dd] = f2bf(val);
                } else {
                    val += bias[n];
                    const int b_ = m>>10, t_ = m&1023;
                    if (MODE == 2) val += bf2f(padd[(size_t)(hh*TT + t_)*64 + dd]);
                    out[((size_t)(b_*HH+hh)*TT + t_)*64 + dd] = f2bf(val);
                }
            }
        }
    }
}

// ---------------------------------------------------------------------------
// Final GEMM: out = ao(f32) @ Wo + bo, hi/lo split bf16 (3-term) for f32
// quality on the direct output path.
// ---------------------------------------------------------------------------
__global__ __launch_bounds__(256) void gemm_final(const float* __restrict__ A,
    const u16* __restrict__ Bhg, const u16* __restrict__ Blg,
    const float* __restrict__ bias, float* __restrict__ out)
{
    __shared__ __align__(16) u16 Ah[128*64];
    __shared__ __align__(16) u16 Al[128*64];
    __shared__ __align__(16) u16 Bh[128*64];
    __shared__ __align__(16) u16 Bl[128*64];
    const int tid = threadIdx.x;
    const int row0 = blockIdx.x*128, col0 = blockIdx.y*128;
    const int wid = tid>>6, lane = tid&63, lm = lane&15, lg = lane>>4;
    const int wm = wid>>1, wn = wid&1;

    f4 acc[4][4];
#pragma unroll
    for (int i=0;i<4;i++)
#pragma unroll
        for (int j=0;j<4;j++) acc[i][j] = (f4){0.f,0.f,0.f,0.f};

    for (int k0=0;k0<NF;k0+=64){
        f4 areg[8]; s8 bhreg[4], blreg[4];
#pragma unroll
        for (int it=0; it<8; ++it){
            int idx = (it*256 + tid)*4;
            int m = idx>>6, k = idx&63;
            areg[it] = *(const f4*)(&A[(size_t)(row0+m)*NF + k0 + k]);
        }
#pragma unroll
        for (int it=0; it<4; ++it){
            int idx = (it*256 + tid)*8;
            int n = idx>>6, k = idx&63;
            bhreg[it] = *(const s8*)(&Bhg[(size_t)(col0+n)*NF + k0 + k]);
            blreg[it] = *(const s8*)(&Blg[(size_t)(col0+n)*NF + k0 + k]);
        }
        __syncthreads();
#pragma unroll
        for (int it=0; it<8; ++it){
            int idx = (it*256+tid)*4;
            int m = idx>>6, k = idx&63;
            us4 ph, pl;
#pragma unroll
            for (int e=0;e<4;e++){
                float x = areg[it][e];
                u16 hi = f2bf(x);
                ph[e] = hi; pl[e] = f2bf(x - bf2f(hi));
            }
            int off = (m*128 + k*2) ^ ((m&7)<<4);
            *(us4*)((char*)Ah + off) = ph;
            *(us4*)((char*)Al + off) = pl;
        }
#pragma unroll
        for (int it=0; it<4; ++it){
            int idx = (it*256+tid)*8;
            int n = idx>>6, k = idx&63;
            int off = (n*128 + k*2) ^ ((n&7)<<4);
            *(s8*)((char*)Bh + off) = bhreg[it];
            *(s8*)((char*)Bl + off) = blreg[it];
        }
        __syncthreads();
#pragma unroll
        for (int c=0;c<2;c++){
            s8 ah[4], al[4], bh4[4], bl4[4];
#pragma unroll
            for (int i=0;i<4;i++){
                int m = wm*64 + i*16 + lm;
                int off = (m*128 + c*64 + lg*16) ^ ((m&7)<<4);
                ah[i] = *(const s8*)((char*)Ah + off);
                al[i] = *(const s8*)((char*)Al + off);
            }
#pragma unroll
            for (int j=0;j<4;j++){
                int n = wn*64 + j*16 + lm;
                int off = (n*128 + c*64 + lg*16) ^ ((n&7)<<4);
                bh4[j] = *(const s8*)((char*)Bh + off);
                bl4[j] = *(const s8*)((char*)Bl + off);
            }
#pragma unroll
            for (int i=0;i<4;i++)
#pragma unroll
                for (int j=0;j<4;j++){
                    acc[i][j] = __builtin_amdgcn_mfma_f32_16x16x32_bf16(al[i], bh4[j], acc[i][j], 0,0,0);
                    acc[i][j] = __builtin_amdgcn_mfma_f32_16x16x32_bf16(ah[i], bl4[j], acc[i][j], 0,0,0);
                    acc[i][j] = __builtin_amdgcn_mfma_f32_16x16x32_bf16(ah[i], bh4[j], acc[i][j], 0,0,0);
                }
        }
    }

#pragma unroll
    for (int i=0;i<4;i++)
#pragma unroll
        for (int j=0;j<4;j++)
#pragma unroll
            for (int r=0;r<4;r++){
                const int m = row0 + wm*64 + i*16 + lg*4 + r;
                const int n = col0 + wn*64 + j*16 + lm;
                out[(size_t)m*NF + n] = acc[i][j][r] + bias[n];
            }
}

// ---------------------------------------------------------------------------
// sb[b,h,s] = ( u[h]·kp[b,h,s] + (v[h]-u[h])·p[h,s] ) / 8 + mask[b,s]
// ---------------------------------------------------------------------------
__global__ __launch_bounds__(256) void sbias_kernel(const u16* __restrict__ kp,
                                                    const u16* __restrict__ p,
                                                    const float* __restrict__ pbu,
                                                    const float* __restrict__ pbv,
                                                    const float* __restrict__ mask,
                                                    float* __restrict__ sb)
{
    const int w    = blockIdx.x * 4 + (threadIdx.x >> 6);
    const int lane = threadIdx.x & 63;
    const int s = w & 1023;
    const int h = (w >> 10) & 7;
    const int b = w >> 13;
    const float u  = pbu[h * 64 + lane];
    const float wv = pbv[h * 64 + lane] - u;
    const float kv = bf2f(kp[((size_t)(b * HH + h) * TT + s) * 64 + lane]);
    const float pv = bf2f(p[(size_t)(h * TT + s) * 64 + lane]);
    float val = u * kv + wv * pv;
#pragma unroll
    for (int off = 32; off; off >>= 1) val += __shfl_xor(val, off);
    if (lane == 0) sb[(size_t)(b * HH + h) * TT + s] = val * 0.125f + mask[b * TT + s];
}

// ---------------------------------------------------------------------------
// Flash attention on MFMA. Block = (b,h,64-row Q tile), 4 waves x 16 rows.
// K LDS [s][d] swz(s); Vt LDS [d][s] swz(d); P LDS [t][s] swz(t).
// In-register online softmax on the C-layout (row = lg*4+r lane-local).
// ---------------------------------------------------------------------------
__global__ __launch_bounds__(256) void attn2(const u16* __restrict__ q,
                                             const u16* __restrict__ kp,
                                             const u16* __restrict__ v,
                                             const float* __restrict__ sb,
                                             float* __restrict__ ao)
{
    __shared__ __align__(16) u16 Ks[64*64];
    __shared__ __align__(16) u16 Vt[64*64];
    __shared__ __align__(16) u16 Ps[64*64];
    __shared__ float sbs[64];

    const int tid = threadIdx.x;
    const int wid = tid>>6, lane = tid&63, lm = lane&15, lg = lane>>4;
    const int t0 = blockIdx.x*64;
    const int h = blockIdx.y, b = blockIdx.z;
    const size_t bh = (size_t)(b*HH + h);
    const u16* qb = q + bh*TT*64;
    const u16* kb = kp + bh*TT*64;
    const u16* vb = v + bh*TT*64;
    const float* sbb = sb + bh*TT;

    // Q fragments in registers (wave's 16 rows)
    s8 qf[2];
    {
        const u16* qr = qb + (size_t)(t0 + wid*16 + lm)*64;
        qf[0] = *(const s8*)(qr + lg*8);
        qf[1] = *(const s8*)(qr + 32 + lg*8);
    }

    float mrow[4], lrow[4];
#pragma unroll
    for (int r=0;r<4;r++){ mrow[r] = -1e30f; lrow[r] = 0.f; }
    f4 oacc[4];
#pragma unroll
    for (int n=0;n<4;n++) oacc[n] = (f4){0.f,0.f,0.f,0.f};

    const int vs_s = tid>>3;   // 0..31
    const int vs_d = tid&7;    // d column group (d = vs_d + 8j)

    for (int s0=0; s0<TT; s0+=64) {
        // ---- load staging data to regs (overlaps previous tile's tail)
        s8 kreg[2]; u16 vreg[2][8];
#pragma unroll
        for (int it=0; it<2; ++it){
            int idx = (it*256 + tid)*8;
            int s = idx>>6, d = idx&63;
            kreg[it] = *(const s8*)(kb + (size_t)(s0+s)*64 + d);
        }
#pragma unroll
        for (int it=0; it<2; ++it){
            int s = vs_s + it*32;
#pragma unroll
            for (int j=0;j<8;j++)
                vreg[it][j] = vb[(size_t)(s0+s)*64 + vs_d + 8*j];
        }
        float sbreg = (tid<64) ? sbb[s0+tid] : 0.f;
        __syncthreads();          // everyone done reading prev K/Vt
#pragma unroll
        for (int it=0; it<2; ++it){
            int idx = (it*256+tid)*8;
            int s = idx>>6, d = idx&63;
            *(s8*)((char*)Ks + ((s*128 + d*2) ^ ((s&7)<<4))) = kreg[it];
        }
#pragma unroll
        for (int it=0; it<2; ++it){
            int s = vs_s + it*32;
#pragma unroll
            for (int j=0;j<8;j++){
                int d = vs_d + 8*j;
                *(u16*)((char*)Vt + ((d*128 + s*2) ^ ((d&7)<<4))) = vreg[it][j];
            }
        }
        if (tid < 64) sbs[tid] = sbreg;
        __syncthreads();

        // ---- QK^T : sc[j] = 16x16 tile (t rows x s cols)
        f4 sc[4];
#pragma unroll
        for (int j=0;j<4;j++) sc[j] = (f4){0.f,0.f,0.f,0.f};
#pragma unroll
        for (int j=0;j<4;j++){
            int n = j*16 + lm;
#pragma unroll
            for (int c=0;c<2;c++){
                s8 bfr = *(const s8*)((char*)Ks + ((n*128 + c*64 + lg*16) ^ ((n&7)<<4)));
                sc[j] = __builtin_amdgcn_mfma_f32_16x16x32_bf16(qf[c], bfr, sc[j], 0,0,0);
            }
        }

        // ---- scale + bias, online softmax (rows are lane-local in r)
        float sbv[4];
#pragma unroll
        for (int j=0;j<4;j++) sbv[j] = sbs[j*16 + lm];
        float x[4][4];   // [j][r]
#pragma unroll
        for (int j=0;j<4;j++)
#pragma unroll
            for (int r=0;r<4;r++) x[j][r] = sc[j][r]*0.125f + sbv[j];

        float cfr[4];
#pragma unroll
        for (int r=0;r<4;r++){
            float rm = fmaxf(fmaxf(x[0][r], x[1][r]), fmaxf(x[2][r], x[3][r]));
#pragma unroll
            for (int off=1; off<16; off<<=1) rm = fmaxf(rm, __shfl_xor(rm, off));
            float nm = fmaxf(mrow[r], rm);
            float cf = __expf(mrow[r] - nm);
            mrow[r] = nm;
            float rs = 0.f;
#pragma unroll
            for (int j=0;j<4;j++){
                float pj = __expf(x[j][r] - nm);
                x[j][r] = pj;
                rs += pj;
            }
#pragma unroll
            for (int off=1; off<16; off<<=1) rs += __shfl_xor(rs, off);
            lrow[r] = lrow[r]*cf + rs;
            cfr[r] = cf;
        }

        // ---- P -> LDS (bf16, swizzled); rows are wave-private
#pragma unroll
        for (int j=0;j<4;j++)
#pragma unroll
            for (int r=0;r<4;r++){
                int t = wid*16 + lg*4 + r;
                int s = j*16 + lm;
                *(u16*)((char*)Ps + ((t*128 + s*2) ^ ((t&7)<<4))) = f2bf(x[j][r]);
            }

        // ---- rescale O, then PV accumulate
#pragma unroll
        for (int n=0;n<4;n++)
#pragma unroll
            for (int r=0;r<4;r++) oacc[n][r] *= cfr[r];

#pragma unroll
        for (int n=0;n<4;n++){
            int drow = n*16 + lm;
#pragma unroll
            for (int c=0;c<2;c++){
                int trow = wid*16 + lm;
                s8 pa  = *(const s8*)((char*)Ps + ((trow*128 + c*64 + lg*16) ^ ((trow&7)<<4)));
                s8 vbf = *(const s8*)((char*)Vt + ((drow*128 + c*64 + lg*16) ^ ((drow&7)<<4)));
                oacc[n] = __builtin_amdgcn_mfma_f32_16x16x32_bf16(pa, vbf, oacc[n], 0,0,0);
            }
        }
    }

    // ---- epilogue: normalize, write ao f32 [b*T+t][h*64+d]
    float inv[4];
#pragma unroll
    for (int r=0;r<4;r++) inv[r] = 1.f / lrow[r];
#pragma unroll
    for (int n=0;n<4;n++)
#pragma unroll
        for (int r=0;r<4;r++){
            int t = t0 + wid*16 + lg*4 + r;
            int d = n*16 + lm;
            ao[((size_t)(b*TT + t))*NF + h*64 + d] = oacc[n][r]*inv[r];
        }
}

// ---------------------------------------------------------------------------
extern "C" void kernel_launch(void* const* d_in, const int* in_sizes, int n_in,
                              void* d_out, int out_size, void* d_ws, size_t ws_size,
                              hipStream_t stream)
{
    const float* query   = (const float*)d_in[0];
    const float* key     = (const float*)d_in[1];
    const float* value   = (const float*)d_in[2];
    const float* pos_emb = (const float*)d_in[3];
    const float* mask    = (const float*)d_in[4];
    const float* Wq   = (const float*)d_in[5];
    const float* bq   = (const float*)d_in[6];
    const float* Wk   = (const float*)d_in[7];
    const float* bk   = (const float*)d_in[8];
    const float* Wv   = (const float*)d_in[9];
    const float* bv   = (const float*)d_in[10];
    const float* Wo   = (const float*)d_in[11];
    const float* bo   = (const float*)d_in[12];
    const float* Wpos = (const float*)d_in[13];
    const float* pbu  = (const float*)d_in[14];
    const float* pbv  = (const float*)d_in[15];
    float* out = (float*)d_out;

    char* ws = (char*)d_ws;
    size_t o = 0;
    u16* wtq  = (u16*)(ws + o); o += (size_t)NF*NF*2;
    u16* wtk  = (u16*)(ws + o); o += (size_t)NF*NF*2;
    u16* wtv  = (u16*)(ws + o); o += (size_t)NF*NF*2;
    u16* wtp  = (u16*)(ws + o); o += (size_t)NF*NF*2;
    u16* wohi = (u16*)(ws + o); o += (size_t)NF*NF*2;
    u16* wolo = (u16*)(ws + o); o += (size_t)NF*NF*2;
    u16* p_ws  = (u16*)(ws + o); o += (size_t)HH*TT*DD*2;
    u16* q_ws  = (u16*)(ws + o); o += (size_t)BB*HH*TT*DD*2;
    u16* kp_ws = (u16*)(ws + o); o += (size_t)BB*HH*TT*DD*2;
    u16* v_ws  = (u16*)(ws + o); o += (size_t)BB*HH*TT*DD*2;
    float* sb_ws = (float*)(ws + o); o += (size_t)BB*HH*TT*4;
    float* ao_ws = (float*)(ws + o); o += (size_t)BB*TT*NF*4;

    const dim3 blk(256);

    prep_w<<<dim3(16,16,5), blk, 0, stream>>>(Wq, Wk, Wv, Wpos, Wo,
                                              wtq, wtk, wtv, wtp, wohi, wolo);
    // p = pos_emb @ Wpos -> bf16 (H,T,D)
    gemm_bf16<0><<<dim3(TT/128, 4), blk, 0, stream>>>(pos_emb, wtp, nullptr, nullptr, p_ws);
    // q / kp / v projections -> bf16 BHTD
    gemm_bf16<1><<<dim3(BB*TT/128, 4), blk, 0, stream>>>(query, wtq, bq, nullptr, q_ws);
    gemm_bf16<2><<<dim3(BB*TT/128, 4), blk, 0, stream>>>(key,   wtk, bk, p_ws,    kp_ws);
    gemm_bf16<1><<<dim3(BB*TT/128, 4), blk, 0, stream>>>(value, wtv, bv, nullptr, v_ws);
    // scalar score bias
    sbias_kernel<<<dim3(BB*HH*TT/4), blk, 0, stream>>>(kp_ws, p_ws, pbu, pbv, mask, sb_ws);
    // fused attention -> ao f32
    attn2<<<dim3(TT/64, HH, BB), blk, 0, stream>>>(q_ws, kp_ws, v_ws, sb_ws, ao_ws);
    // out = ao @ Wo + bo (hi/lo split)
    gemm_final<<<dim3(BB*TT/128, 4), blk, 0, stream>>>(ao_ws, wohi, wolo, bo, out);
}